// Round 1
// baseline (617.442 us; speedup 1.0000x reference)
//
#include <hip/hip_runtime.h>
#include <stdint.h>

#define NN 100000      // nodes
#define EE 500000      // edges
#define HIDD 256
#define LN_EPS 1e-5f

typedef _Float16 half8 __attribute__((ext_vector_type(8)));  // 8 fp16 (4 VGPRs)
typedef _Float16 half4 __attribute__((ext_vector_type(4)));
typedef __fp16 fp16x2 __attribute__((ext_vector_type(2)));   // builtin return type
typedef float f32x4 __attribute__((ext_vector_type(4)));
typedef float f32x2 __attribute__((ext_vector_type(2)));     // v_pk_*_f32 carrier

// lgkm-only barrier: makes LDS writes visible WITHOUT draining vmcnt (global loads
// stay in flight across it — the fine-grained vmcnt pattern __syncthreads forbids).
#define LBAR() asm volatile("s_waitcnt lgkmcnt(0)\n\ts_barrier" ::: "memory")

__device__ __forceinline__ unsigned short f2h(float f) {
  _Float16 h = (_Float16)f;                 // v_cvt_f16_f32, RNE
  union { _Float16 hh; unsigned short us; } u; u.hh = h;
  return u.us;
}

__device__ __forceinline__ unsigned pkrtz(float a, float b) {
  union { fp16x2 h; unsigned u; } c;
  c.h = __builtin_amdgcn_cvt_pkrtz(a, b);   // 1 instr: 2×f32 -> packed fp16
  return c.u;
}

__device__ __forceinline__ float fast_silu(float y) {
  float e = __expf(-y);
  return y * __builtin_amdgcn_rcpf(1.f + e);     // rcp instead of full div
}

__device__ __forceinline__ half8 ldg8(const unsigned short* p) {
  return *(const half8*)p;                  // global_load_dwordx4
}

// fp32 row-piece -> packed fp16 int4 (use_hb=0 fallback; row-at-a-time to bound
// transient VGPR pressure under the tighter 128-reg budget)
__device__ __forceinline__ int4 cvt_row(const float* s) {
  float4 a0 = *(const float4*)s, a1 = *(const float4*)(s + 4);
  uint4 ua;
  ua.x = pkrtz(a0.x, a0.y); ua.y = pkrtz(a0.z, a0.w);
  ua.z = pkrtz(a1.x, a1.y); ua.w = pkrtz(a1.z, a1.w);
  return *(int4*)&ua;
}

// ---- merged prep: weight swizzle (blocks 0..711) + h f32->fp16 (blocks 712..13211) ----
__global__ __launch_bounds__(256) void prep_kern(const float* __restrict__ h,
                                                 const float* __restrict__ W1,
                                                 const float* __restrict__ W2,
                                                 const float* __restrict__ W3,
                                                 unsigned short* __restrict__ hb,
                                                 unsigned short* __restrict__ w1sw,
                                                 unsigned short* __restrict__ w2sw,
                                                 unsigned short* __restrict__ w3sw) {
  int b = blockIdx.x;
  if (b < 712) {
    int t = b * 256 + threadIdx.x;
    if (t < 147456) {
      int chunk = t >> 14, rem = t & 16383;
      int kq = rem >> 11, n = (rem >> 3) & 255, j = rem & 7;
      int k = (chunk << 6) + (kq << 3) + j;
      float v = (k < 551) ? W1[k * 256 + n] : 0.f;
      w1sw[t] = f2h(v);
    } else if (t < 147456 + 32768) {
      int t2 = t - 147456;
      int chunk = t2 >> 13, rem = t2 & 8191;
      int kq = rem >> 10, n = (rem >> 3) & 127, j = rem & 7;
      int k = (chunk << 6) + (kq << 3) + j;
      w2sw[t2] = f2h(W2[k * 128 + n]);
    } else if (t < 147456 + 32768 + 2048) {
      int t3 = t - 180224;
      int kq = t3 >> 7, o = (t3 >> 3) & 15, j = t3 & 7;
      int k = (kq << 3) + j;
      w3sw[t3] = f2h((o < 5) ? W3[k * 5 + o] : 0.f);
    }
  } else {
    int i = ((b - 712) * 256 + threadIdx.x) * 8;   // N*HID = 25.6M = 12500*256*8
    float4 v0 = *(const float4*)(h + i);
    float4 v1 = *(const float4*)(h + i + 4);
    uint4 u;
    u.x = pkrtz(v0.x, v0.y); u.y = pkrtz(v0.z, v0.w);
    u.z = pkrtz(v1.x, v1.y); u.w = pkrtz(v1.z, v1.w);
    *(uint4*)(hb + i) = u;
  }
}

// ---- fused main kernel: 64 edges/block, 256 threads (4 waves), 4 blocks/CU ----
// W1/W2/W3 fragments load DIRECTLY global->VGPR (zero intra-block sharing; L1/L2
// serve cross-block reuse). LDS holds only block-local data: feats dbuf, z1T, z2T.
// All barriers are lgkm-only — global loads are never force-drained.
// A-frag: A[m=lane&15][k=(lane>>4)*8+j];  B-frag: B[k=(lane>>4)*8+j][n=lane&15]
// D: row m=(lane>>4)*4+reg (channel), col n=lane&15 (edge)
// feats/z1T/z2T XOR-swizzled: elem(row,k) at row*S + (k ^ ((row&7)<<3)).
// Register budget note: W1 frags rotate at HALF-chunk (ks) granularity — fA/fB =
// 32 VGPR vs the old fcur/fnext 64 — so total regs fit 4 waves/SIMD (128 budget);
// LDS at 37.9KB also admits 4 blocks/CU. Occupancy was the measured limiter (32%).
struct __align__(16) SMem {
  short r1[16384];    // 32768B: feats dbuf (2x4096el) in GEMM1 -> z1T [64][256]swz -> z2T [64][128]swz (head)
  float red[512];     // 2048B : LN partial sums (S in [0..255], Q in [256..511]) -> out staging (320f)
  _Float16 b1h[256], g1h[256], be1h[256];   // 1536B
  _Float16 b2h[128], g2h[128], be2h[128];   // 768B
  float muv[16];      // 64B
  float b3v[8];       // 32B
  int spI[64], exI[64];                     // 512B
};  // ~37.7 KB

__global__ __launch_bounds__(256, 4)
void edge_head_main(const float* __restrict__ h, const float* __restrict__ x,
                    const int* __restrict__ spawn, const int* __restrict__ exist,
                    const float* __restrict__ insx, const int* __restrict__ insa,
                    const int* __restrict__ insc,
                    const float* __restrict__ b1, const float* __restrict__ g1,
                    const float* __restrict__ be1,
                    const float* __restrict__ b2, const float* __restrict__ g2,
                    const float* __restrict__ be2,
                    const float* __restrict__ b3, const float* __restrict__ mu,
                    const float* __restrict__ gammaP,
                    const unsigned short* __restrict__ w1sw,
                    const unsigned short* __restrict__ w2sw,
                    const unsigned short* __restrict__ w3swg,
                    const unsigned short* __restrict__ hb, int use_hb,
                    float* __restrict__ out) {
  __shared__ SMem sm;
  const int t = threadIdx.x;
  const int base = blockIdx.x * 64;
  const int lane = t & 63;
  const int wv = t >> 6;
  const int cl = lane & 15;
  const int q = lane >> 4;
  const int sx = (cl & 7) << 3;    // B-frag read swizzle term

  // ---- const staging ----
  sm.b1h[t] = (_Float16)b1[t]; sm.g1h[t] = (_Float16)g1[t]; sm.be1h[t] = (_Float16)be1[t];
  if (t < 128) { sm.b2h[t] = (_Float16)b2[t]; sm.g2h[t] = (_Float16)g2[t]; sm.be2h[t] = (_Float16)be2[t]; }
  if (t < 16) sm.muv[t] = mu[t];
  if (t < 8) sm.b3v[t] = (t < 5) ? b3[t] : 0.f;
  if (t < 64) {
    int e = base + t; int ec = e < EE ? e : EE - 1;
    sm.spI[t] = spawn[ec]; sm.exI[t] = exist[ec];
  }
  const float gma = gammaP[0];

  LBAR();   // B0: indices + consts visible

  // ---- distance + one-hot positions only (RBF exp deferred to chunk-8 slot:
  //      holding d/k1/k2 costs 3 VGPR vs 8 for the old packed f8a/f8b) ----
  float dreg = 0.f;
  int k1 = 16, k2 = 32;
  if (t < 64) {
    int e = base + t; int ec = e < EE ? e : EE - 1;
    float ix0 = insx[ec * 3], ix1 = insx[ec * 3 + 1], ix2 = insx[ec * 3 + 2];
    int nd = sm.exI[t];
    float dx = ix0 - x[nd * 3], dy = ix1 - x[nd * 3 + 1], dz = ix2 - x[nd * 3 + 2];
    dreg = fmaxf(sqrtf(dx * dx + dy * dy + dz * dz), 1e-6f);
    k1 = 16 + insa[ec]; k2 = 32 + insc[ec];
  }

  // gather slots: thread fills feats rows row0 (16B piece p0) and row1 (=row0+32)
  const int row0 = t >> 3, p0 = t & 7;
  const int row1 = row0 + 32;
  const int sw0 = ((p0 ^ (row0 & 7)) << 3);
  const int sw1 = ((p0 ^ (row1 & 7)) << 3);

  // chunk 0 gather (spawn, colb=0)
  int4 pA, pB;
  if (use_hb) {
    pA = *(const int4*)(hb + (size_t)sm.spI[row0] * HIDD + p0 * 8);
    pB = *(const int4*)(hb + (size_t)sm.spI[row1] * HIDD + p0 * 8);
  } else {
    pA = cvt_row(h + (size_t)sm.spI[row0] * HIDD + p0 * 8);
    pB = cvt_row(h + (size_t)sm.spI[row1] * HIDD + p0 * 8);
  }
  // write chunk 0 -> buf0
  *(int4*)&sm.r1[row0 * 64 + sw0] = pA;
  *(int4*)&sm.r1[row1 * 64 + sw1] = pB;
  // issue chunk 1 gather (spawn, colb=64)
  if (use_hb) {
    pA = *(const int4*)(hb + (size_t)sm.spI[row0] * HIDD + 64 + p0 * 8);
    pB = *(const int4*)(hb + (size_t)sm.spI[row1] * HIDD + 64 + p0 * 8);
  } else {
    pA = cvt_row(h + (size_t)sm.spI[row0] * HIDD + 64 + p0 * 8);
    pB = cvt_row(h + (size_t)sm.spI[row1] * HIDD + 64 + p0 * 8);
  }

  // W1 fragment base for this thread (direct global->reg); preload chunk-0 halves
  const unsigned short* w1p = w1sw + q * 2048 + wv * 512 + cl * 8;
  half8 fA[4], fB[4];
#pragma unroll
  for (int i = 0; i < 4; ++i) fA[i] = ldg8(w1p + i * 128);
#pragma unroll
  for (int i = 0; i < 4; ++i) fB[i] = ldg8(w1p + 8192 + i * 128);

  LBAR();   // buf0 visible

  // ---- GEMM1: z1^T[256][64] = W1^T * feats^T, K = 576 in 9 chunks of 64 ----
  f32x4 acc[4][4];
#pragma unroll
  for (int i = 0; i < 4; ++i)
#pragma unroll
    for (int j = 0; j < 4; ++j) acc[i][j] = (f32x4){0.f, 0.f, 0.f, 0.f};

#pragma unroll
  for (int c = 0; c < 9; ++c) {
    // stage feats chunk c+1 into buf[(c+1)&1]; prefetch chunk c+2
    if (c < 7) {
      const int nb = ((c + 1) & 1) * 4096;
      *(int4*)&sm.r1[nb + row0 * 64 + sw0] = pA;   // vmcnt wait auto (data dep)
      *(int4*)&sm.r1[nb + row1 * 64 + sw1] = pB;
      if (c < 6) {
        const int cn = c + 2;
        const int* sel = (cn < 4) ? sm.spI : sm.exI;
        const int colb = (cn & 3) * 64;
        if (use_hb) {
          pA = *(const int4*)(hb + (size_t)sel[row0] * HIDD + colb + p0 * 8);
          pB = *(const int4*)(hb + (size_t)sel[row1] * HIDD + colb + p0 * 8);
        } else {
          pA = cvt_row(h + (size_t)sel[row0] * HIDD + colb + p0 * 8);
          pB = cvt_row(h + (size_t)sel[row1] * HIDD + colb + p0 * 8);
        }
      }
    } else if (c == 7) {
      // chunk 8 = built features -> buf0 (RBF exp computed here, wave 0 only)
      if (t < 64) {
        short* rp = &sm.r1[t * 64];   // (8&1)=0 -> buf0
        const int sw = t & 7;
        float rb[16];
#pragma unroll
        for (int k = 0; k < 16; ++k) { float dd = dreg - sm.muv[k]; rb[k] = __expf(-gma * dd * dd); }
        uint4 ua, ub;
        ua.x = pkrtz(rb[0], rb[1]);  ua.y = pkrtz(rb[2], rb[3]);
        ua.z = pkrtz(rb[4], rb[5]);  ua.w = pkrtz(rb[6], rb[7]);
        ub.x = pkrtz(rb[8], rb[9]);  ub.y = pkrtz(rb[10], rb[11]);
        ub.z = pkrtz(rb[12], rb[13]); ub.w = pkrtz(rb[14], rb[15]);
        *(int4*)&rp[(0 ^ sw) * 8] = *(int4*)&ua;
        *(int4*)&rp[(1 ^ sw) * 8] = *(int4*)&ub;
        const int4 z4 = {0, 0, 0, 0};
#pragma unroll
        for (int g = 2; g < 8; ++g) *(int4*)&rp[(g ^ sw) * 8] = z4;
        rp[((k1 >> 3) ^ sw) * 8 + (k1 & 7)] = (short)0x3C00;   // fp16 1.0
        rp[((k2 >> 3) ^ sw) * 8 + (k2 & 7)] = (short)0x3C00;
      }
    }
    // MFMA chunk c from buf[c&1]; W1 frag halves rotate (reload right after use)
    const int cb = (c & 1) * 4096;
    {
      half8 bf[4];
#pragma unroll
      for (int j = 0; j < 4; ++j)
        bf[j] = *(const half8*)&sm.r1[cb + (j * 16 + cl) * 64 + ((q * 8) ^ sx)];
#pragma unroll
      for (int i = 0; i < 4; ++i)
#pragma unroll
        for (int j = 0; j < 4; ++j)
          acc[i][j] = __builtin_amdgcn_mfma_f32_16x16x32_f16(fA[i], bf[j], acc[i][j], 0, 0, 0);
    }
    if (c < 8) {
      const unsigned short* wp = w1p + (c + 1) * 16384;
#pragma unroll
      for (int i = 0; i < 4; ++i) fA[i] = ldg8(wp + i * 128);
    }
    {
      half8 bf[4];
#pragma unroll
      for (int j = 0; j < 4; ++j)
        bf[j] = *(const half8*)&sm.r1[cb + (j * 16 + cl) * 64 + ((32 + q * 8) ^ sx)];
#pragma unroll
      for (int i = 0; i < 4; ++i)
#pragma unroll
        for (int j = 0; j < 4; ++j)
          acc[i][j] = __builtin_amdgcn_mfma_f32_16x16x32_f16(fB[i], bf[j], acc[i][j], 0, 0, 0);
    }
    if (c < 8) {
      const unsigned short* wp = w1p + (c + 1) * 16384 + 8192;
#pragma unroll
      for (int i = 0; i < 4; ++i) fB[i] = ldg8(wp + i * 128);
    }
    LBAR();   // chunk c+1 writes visible; all waves done with buf[c&1]
  }

  // ---- +b1 (fused), LN over 256 channels, SiLU, pack to z1T ----
  // packed-f32 (v_pk_add/v_pk_fma) form: halves the VALU count of bias/S/Q
  f32x2 bb1[4][2];
#pragma unroll
  for (int i = 0; i < 4; ++i) {
    half4 b4 = *(const half4*)&sm.b1h[wv * 64 + i * 16 + q * 4];
    bb1[i][0] = (f32x2){(float)b4[0], (float)b4[1]};
    bb1[i][1] = (f32x2){(float)b4[2], (float)b4[3]};
  }
  float S1arr[4], Q1arr[4];
#pragma unroll
  for (int j = 0; j < 4; ++j) {
    f32x2 S2 = (f32x2){0.f, 0.f}, Q2 = (f32x2){0.f, 0.f};
#pragma unroll
    for (int i = 0; i < 4; ++i) {
      f32x2 v0 = (f32x2){acc[i][j][0], acc[i][j][1]} + bb1[i][0];
      f32x2 v1 = (f32x2){acc[i][j][2], acc[i][j][3]} + bb1[i][1];
      acc[i][j][0] = v0[0]; acc[i][j][1] = v0[1];
      acc[i][j][2] = v1[0]; acc[i][j][3] = v1[1];
      S2 += v0 + v1;
      Q2 += v0 * v0;        // contracts to v_pk_fma_f32
      Q2 += v1 * v1;
    }
    float S = S2[0] + S2[1], Q = Q2[0] + Q2[1];
    S += __shfl_xor(S, 16); S += __shfl_xor(S, 32);
    Q += __shfl_xor(Q, 16); Q += __shfl_xor(Q, 32);
    S1arr[j] = S; Q1arr[j] = Q;
  }
  if (q == 0) {
#pragma unroll
    for (int j = 0; j < 4; ++j) {
      sm.red[wv * 64 + j * 16 + cl] = S1arr[j];
      sm.red[256 + wv * 64 + j * 16 + cl] = Q1arr[j];
    }
  }
  LBAR();   // red1 visible; all waves past GEMM1 -> r1 reusable as z1T
  f32x2 rs1[4], mr1[4];      // {rstd,rstd}, {-mean*rstd,-mean*rstd}
#pragma unroll
  for (int j = 0; j < 4; ++j) {
    int m = j * 16 + cl;
    float S = sm.red[m] + sm.red[64 + m] + sm.red[128 + m] + sm.red[192 + m];
    float Q = sm.red[256 + m] + sm.red[320 + m] + sm.red[384 + m] + sm.red[448 + m];
    float mn = S * (1.f / 256.f);
    float rs = rsqrtf(Q * (1.f / 256.f) - mn * mn + LN_EPS);
    rs1[j] = (f32x2){rs, rs};
    mr1[j] = (f32x2){-mn * rs, -mn * rs};
  }
#pragma unroll
  for (int i = 0; i < 4; ++i) {
    half4 g4 = *(const half4*)&sm.g1h[wv * 64 + i * 16 + q * 4];
    half4 e4 = *(const half4*)&sm.be1h[wv * 64 + i * 16 + q * 4];
    f32x2 gg0 = (f32x2){(float)g4[0], (float)g4[1]}, gg1 = (f32x2){(float)g4[2], (float)g4[3]};
    f32x2 ee0 = (f32x2){(float)e4[0], (float)e4[1]}, ee1 = (f32x2){(float)e4[2], (float)e4[3]};
#pragma unroll
    for (int j = 0; j < 4; ++j) {
      f32x2 v0 = (f32x2){acc[i][j][0], acc[i][j][1]};
      f32x2 v1 = (f32x2){acc[i][j][2], acc[i][j][3]};
      f32x2 t0 = v0 * rs1[j] + mr1[j];    // (v-mean)*rstd as one pk_fma
      f32x2 t1 = v1 * rs1[j] + mr1[j];
      f32x2 y0 = t0 * gg0 + ee0;
      f32x2 y1 = t1 * gg1 + ee1;
      float s0 = fast_silu(y0[0]), s1 = fast_silu(y0[1]);
      float s2 = fast_silu(y1[0]), s3 = fast_silu(y1[1]);
      uint2 w; w.x = pkrtz(s0, s1); w.y = pkrtz(s2, s3);
      int m = j * 16 + cl;
      int k0 = wv * 64 + i * 16 + q * 4;
      *(uint2*)&sm.r1[m * 256 + (k0 ^ ((m & 7) << 3))] = w;   // z1T swz
    }
  }
  LBAR();   // z1T visible

  // W3 fragments: issue early, consumed at GEMM3 (vmcnt interleave)
  half8 af3[4];
#pragma unroll
  for (int ks = 0; ks < 4; ++ks)
    af3[ks] = ldg8(w3swg + (ks * 4 + q) * 128 + cl * 8);

  // ---- GEMM2: z2^T[128][64] = W2^T * z1^T — barrier-free, W2 direct-to-reg ----
  const unsigned short* w2p = w2sw + q * 1024 + wv * 256 + cl * 8;
  f32x4 acc2[2][4];
#pragma unroll
  for (int i = 0; i < 2; ++i)
#pragma unroll
    for (int j = 0; j < 4; ++j) acc2[i][j] = (f32x4){0.f, 0.f, 0.f, 0.f};
#pragma unroll
  for (int c2 = 0; c2 < 4; ++c2) {
#pragma unroll
    for (int ks = 0; ks < 2; ++ks) {
      half8 a0 = ldg8(w2p + c2 * 8192 + ks * 4096);
      half8 a1 = ldg8(w2p + c2 * 8192 + ks * 4096 + 128);
      half8 bf[4];
#pragma unroll
      for (int j = 0; j < 4; ++j)
        bf[j] = *(const half8*)&sm.r1[(j * 16 + cl) * 256 + ((c2 * 64 + ks * 32 + q * 8) ^ sx)];
#pragma unroll
      for (int j = 0; j < 4; ++j) {
        acc2[0][j] = __builtin_amdgcn_mfma_f32_16x16x32_f16(a0, bf[j], acc2[0][j], 0, 0, 0);
        acc2[1][j] = __builtin_amdgcn_mfma_f32_16x16x32_f16(a1, bf[j], acc2[1][j], 0, 0, 0);
      }
    }
  }

  // ---- +b2 (fused), LN over 128, SiLU, pack z2T (overlays z1T head in r1) ----
  f32x2 bb2[2][2];
#pragma unroll
  for (int i = 0; i < 2; ++i) {
    half4 b4 = *(const half4*)&sm.b2h[wv * 32 + i * 16 + q * 4];
    bb2[i][0] = (f32x2){(float)b4[0], (float)b4[1]};
    bb2[i][1] = (f32x2){(float)b4[2], (float)b4[3]};
  }
  float S2arr[4], Q2arr[4];
#pragma unroll
  for (int j = 0; j < 4; ++j) {
    f32x2 S2 = (f32x2){0.f, 0.f}, Q2 = (f32x2){0.f, 0.f};
#pragma unroll
    for (int i = 0; i < 2; ++i) {
      f32x2 v0 = (f32x2){acc2[i][j][0], acc2[i][j][1]} + bb2[i][0];
      f32x2 v1 = (f32x2){acc2[i][j][2], acc2[i][j][3]} + bb2[i][1];
      acc2[i][j][0] = v0[0]; acc2[i][j][1] = v0[1];
      acc2[i][j][2] = v1[0]; acc2[i][j][3] = v1[1];
      S2 += v0 + v1;
      Q2 += v0 * v0;
      Q2 += v1 * v1;
    }
    float S = S2[0] + S2[1], Q = Q2[0] + Q2[1];
    S += __shfl_xor(S, 16); S += __shfl_xor(S, 32);
    Q += __shfl_xor(Q, 16); Q += __shfl_xor(Q, 32);
    S2arr[j] = S; Q2arr[j] = Q;
  }
  if (q == 0) {
#pragma unroll
    for (int j = 0; j < 4; ++j) {
      sm.red[wv * 64 + j * 16 + cl] = S2arr[j];
      sm.red[256 + wv * 64 + j * 16 + cl] = Q2arr[j];
    }
  }
  LBAR();   // red2 visible; all waves past GEMM2 -> z1T dead, z2T region safe
  f32x2 rs2[4], mr2[4];
#pragma unroll
  for (int j = 0; j < 4; ++j) {
    int m = j * 16 + cl;
    float S = sm.red[m] + sm.red[64 + m] + sm.red[128 + m] + sm.red[192 + m];
    float Q = sm.red[256 + m] + sm.red[320 + m] + sm.red[384 + m] + sm.red[448 + m];
    float mn = S * (1.f / 128.f);
    float rs = rsqrtf(Q * (1.f / 128.f) - mn * mn + LN_EPS);
    rs2[j] = (f32x2){rs, rs};
    mr2[j] = (f32x2){-mn * rs, -mn * rs};
  }
#pragma unroll
  for (int i = 0; i < 2; ++i) {
    half4 g4 = *(const half4*)&sm.g2h[wv * 32 + i * 16 + q * 4];
    half4 e4 = *(const half4*)&sm.be2h[wv * 32 + i * 16 + q * 4];
    f32x2 gg0 = (f32x2){(float)g4[0], (float)g4[1]}, gg1 = (f32x2){(float)g4[2], (float)g4[3]};
    f32x2 ee0 = (f32x2){(float)e4[0], (float)e4[1]}, ee1 = (f32x2){(float)e4[2], (float)e4[3]};
#pragma unroll
    for (int j = 0; j < 4; ++j) {
      f32x2 v0 = (f32x2){acc2[i][j][0], acc2[i][j][1]};
      f32x2 v1 = (f32x2){acc2[i][j][2], acc2[i][j][3]};
      f32x2 t0 = v0 * rs2[j] + mr2[j];
      f32x2 t1 = v1 * rs2[j] + mr2[j];
      f32x2 y0 = t0 * gg0 + ee0;
      f32x2 y1 = t1 * gg1 + ee1;
      float s0 = fast_silu(y0[0]), s1 = fast_silu(y0[1]);
      float s2 = fast_silu(y1[0]), s3 = fast_silu(y1[1]);
      uint2 w; w.x = pkrtz(s0, s1); w.y = pkrtz(s2, s3);
      int m = j * 16 + cl;
      int k0 = wv * 32 + i * 16 + q * 4;
      *(uint2*)&sm.r1[m * 128 + (k0 ^ ((m & 7) << 3))] = w;   // z2T swz (r1 head)
    }
  }
  LBAR();   // z2T visible

  // ---- GEMM3: out^T[16][64] = W3^T * z2^T (o padded 5->16) ----
  f32x4 a3 = (f32x4){0.f, 0.f, 0.f, 0.f};
  const int m3 = wv * 16 + cl;
  const int sx3 = (m3 & 7) << 3;
#pragma unroll
  for (int ks = 0; ks < 4; ++ks) {
    half8 bfv = *(const half8*)&sm.r1[m3 * 128 + ((ks * 32 + q * 8) ^ sx3)];
    a3 = __builtin_amdgcn_mfma_f32_16x16x32_f16(af3[ks], bfv, a3, 0, 0, 0);
  }
  // stage the 64x5 output tile in LDS (red[] is dead) and write coalesced float4s:
  // the old masked strided 4B stores amplified WRITE_SIZE ~9x at sector granularity.
#pragma unroll
  for (int r = 0; r < 4; ++r) {
    int o = q * 4 + r;
    if (o < 5) sm.red[m3 * 5 + o] = a3[r] + sm.b3v[o];
  }
  LBAR();   // out tile visible
  if (t < 80) {
    size_t g = (size_t)base * 5 + (size_t)t * 4;
    if (g + 4 <= (size_t)EE * 5) {
      *(float4*)(out + g) = *(const float4*)&sm.red[t * 4];
    } else {
#pragma unroll
      for (int u = 0; u < 4; ++u)
        if (g + u < (size_t)EE * 5) out[g + u] = sm.red[t * 4 + u];
    }
  }
}

extern "C" void kernel_launch(void* const* d_in, const int* in_sizes, int n_in,
                              void* d_out, int out_size, void* d_ws, size_t ws_size,
                              hipStream_t stream) {
  const float* h    = (const float*)d_in[0];
  const float* x    = (const float*)d_in[1];
  const int* spawn  = (const int*)d_in[2];
  const int* exist  = (const int*)d_in[3];
  const float* insx = (const float*)d_in[4];
  const int* insa   = (const int*)d_in[5];
  const int* insc   = (const int*)d_in[6];
  const float* W1   = (const float*)d_in[7];
  const float* b1   = (const float*)d_in[8];
  const float* g1   = (const float*)d_in[9];
  const float* be1  = (const float*)d_in[10];
  const float* W2   = (const float*)d_in[11];
  const float* b2   = (const float*)d_in[12];
  const float* g2   = (const float*)d_in[13];
  const float* be2  = (const float*)d_in[14];
  const float* W3   = (const float*)d_in[15];
  const float* b3   = (const float*)d_in[16];
  const float* mu   = (const float*)d_in[17];
  const float* gma  = (const float*)d_in[18];

  unsigned short* w1sw = (unsigned short*)d_ws;          // 147456 el
  unsigned short* w2sw = w1sw + 147456;                  // 32768 el
  unsigned short* w3sw = w2sw + 32768;                   // 2048 el
  unsigned short* hb   = w3sw + 2048;                    // N*HID el (optional)
  const size_t need_hb = 364544ull + (size_t)NN * HIDD * 2ull;
  int use_hb = (ws_size >= need_hb) ? 1 : 0;

  prep_kern<<<use_hb ? 13212 : 712, 256, 0, stream>>>(h, W1, W2, W3, hb, w1sw, w2sw, w3sw);
  edge_head_main<<<7813, 256, 0, stream>>>(h, x, spawn, exist, insx, insa, insc,
                                           b1, g1, be1, b2, g2, be2, b3, mu, gma,
                                           w1sw, w2sw, w3sw, hb, use_hb,
                                           (float*)d_out);
}

// Round 2
// 492.292 us; speedup vs baseline: 1.2542x; 1.2542x over previous
//
#include <hip/hip_runtime.h>
#include <stdint.h>

#define NN 100000      // nodes
#define EE 500000      // edges
#define HIDD 256
#define LN_EPS 1e-5f

typedef _Float16 half8 __attribute__((ext_vector_type(8)));  // 8 fp16 (4 VGPRs)
typedef _Float16 half4 __attribute__((ext_vector_type(4)));
typedef __fp16 fp16x2 __attribute__((ext_vector_type(2)));   // builtin return type
typedef float f32x4 __attribute__((ext_vector_type(4)));
typedef float f32x2 __attribute__((ext_vector_type(2)));     // v_pk_*_f32 carrier

// lgkm-only barrier: makes LDS writes visible WITHOUT draining vmcnt (global loads
// stay in flight across it — the fine-grained vmcnt pattern __syncthreads forbids).
#define LBAR() asm volatile("s_waitcnt lgkmcnt(0)\n\ts_barrier" ::: "memory")

__device__ __forceinline__ unsigned short f2h(float f) {
  _Float16 h = (_Float16)f;                 // v_cvt_f16_f32, RNE
  union { _Float16 hh; unsigned short us; } u; u.hh = h;
  return u.us;
}

__device__ __forceinline__ unsigned pkrtz(float a, float b) {
  union { fp16x2 h; unsigned u; } c;
  c.h = __builtin_amdgcn_cvt_pkrtz(a, b);   // 1 instr: 2×f32 -> packed fp16
  return c.u;
}

__device__ __forceinline__ float fast_silu(float y) {
  float e = __expf(-y);
  return y * __builtin_amdgcn_rcpf(1.f + e);     // rcp instead of full div
}

__device__ __forceinline__ half8 ldg8(const unsigned short* p) {
  return *(const half8*)p;                  // global_load_dwordx4
}

// fp32 row-piece -> packed fp16 int4 (use_hb=0 fallback)
__device__ __forceinline__ int4 cvt_row(const float* s) {
  float4 a0 = *(const float4*)s, a1 = *(const float4*)(s + 4);
  uint4 ua;
  ua.x = pkrtz(a0.x, a0.y); ua.y = pkrtz(a0.z, a0.w);
  ua.z = pkrtz(a1.x, a1.y); ua.w = pkrtz(a1.z, a1.w);
  return *(int4*)&ua;
}

// ---- merged prep: weight swizzle (blocks 0..711) + h f32->fp16 (blocks 712..13211) ----
__global__ __launch_bounds__(256) void prep_kern(const float* __restrict__ h,
                                                 const float* __restrict__ W1,
                                                 const float* __restrict__ W2,
                                                 const float* __restrict__ W3,
                                                 unsigned short* __restrict__ hb,
                                                 unsigned short* __restrict__ w1sw,
                                                 unsigned short* __restrict__ w2sw,
                                                 unsigned short* __restrict__ w3sw) {
  int b = blockIdx.x;
  if (b < 712) {
    int t = b * 256 + threadIdx.x;
    if (t < 147456) {
      int chunk = t >> 14, rem = t & 16383;
      int kq = rem >> 11, n = (rem >> 3) & 255, j = rem & 7;
      int k = (chunk << 6) + (kq << 3) + j;
      float v = (k < 551) ? W1[k * 256 + n] : 0.f;
      w1sw[t] = f2h(v);
    } else if (t < 147456 + 32768) {
      int t2 = t - 147456;
      int chunk = t2 >> 13, rem = t2 & 8191;
      int kq = rem >> 10, n = (rem >> 3) & 127, j = rem & 7;
      int k = (chunk << 6) + (kq << 3) + j;
      w2sw[t2] = f2h(W2[k * 128 + n]);
    } else if (t < 147456 + 32768 + 2048) {
      int t3 = t - 180224;
      int kq = t3 >> 7, o = (t3 >> 3) & 15, j = t3 & 7;
      int k = (kq << 3) + j;
      w3sw[t3] = f2h((o < 5) ? W3[k * 5 + o] : 0.f);
    }
  } else {
    int i = ((b - 712) * 256 + threadIdx.x) * 8;   // N*HID = 25.6M = 12500*256*8
    float4 v0 = *(const float4*)(h + i);
    float4 v1 = *(const float4*)(h + i + 4);
    uint4 u;
    u.x = pkrtz(v0.x, v0.y); u.y = pkrtz(v0.z, v0.w);
    u.z = pkrtz(v1.x, v1.y); u.w = pkrtz(v1.z, v1.w);
    *(uint4*)(hb + i) = u;
  }
}

// ---- fused main kernel: 64 edges/block, 512 threads (8 waves), 2 blocks/CU ----
// Round-1 lesson: 256t/4blk forced spills (WRITE_SIZE 95.7->958MB). Instead the
// accumulator itself is halved by splitting GEMM1/2 output channels across 8
// waves: acc[2][4]=32 VGPR, frag dbuf 32, gather 4 -> ~115 live regs fits the
// 128 budget of __launch_bounds__(512,4) => 16 waves/CU (50%) WITHOUT spilling.
// W1/W2/W3 fragments load DIRECTLY global->VGPR; LDS holds block-local data only.
// All barriers lgkm-only. Swizzle: elem(row,k) at row*S + (k ^ ((row&7)<<3)).
// A-frag: A[m=lane&15][k=(lane>>4)*8+j];  B-frag: B[k=(lane>>4)*8+j][n=lane&15]
// D: row m=(lane>>4)*4+reg (channel), col n=lane&15 (edge)
struct __align__(16) SMem {
  short r1[16384];    // 32768B: feats dbuf (2x4096el) in GEMM1 -> z1T [64][256]swz -> z2T [64][128]swz (head)
  float red[1024];    // 4096B : LN partials (S [0..511], Q [512..1023]) -> out staging (320f)
  _Float16 b1h[256], g1h[256], be1h[256];   // 1536B
  _Float16 b2h[128], g2h[128], be2h[128];   // 768B
  float muv[16];      // 64B
  float b3v[8];       // 32B
  int spI[64], exI[64];                     // 512B
};  // ~38.8 KB

__global__ __launch_bounds__(512, 4)
void edge_head_main(const float* __restrict__ h, const float* __restrict__ x,
                    const int* __restrict__ spawn, const int* __restrict__ exist,
                    const float* __restrict__ insx, const int* __restrict__ insa,
                    const int* __restrict__ insc,
                    const float* __restrict__ b1, const float* __restrict__ g1,
                    const float* __restrict__ be1,
                    const float* __restrict__ b2, const float* __restrict__ g2,
                    const float* __restrict__ be2,
                    const float* __restrict__ b3, const float* __restrict__ mu,
                    const float* __restrict__ gammaP,
                    const unsigned short* __restrict__ w1sw,
                    const unsigned short* __restrict__ w2sw,
                    const unsigned short* __restrict__ w3swg,
                    const unsigned short* __restrict__ hb, int use_hb,
                    float* __restrict__ out) {
  __shared__ SMem sm;
  const int t = threadIdx.x;
  const int base = blockIdx.x * 64;
  const int lane = t & 63;
  const int wv = t >> 6;           // 0..7
  const int cl = lane & 15;
  const int q = lane >> 4;
  const int sx = (cl & 7) << 3;    // B-frag read swizzle term

  // ---- const staging ----
  if (t < 256) { sm.b1h[t] = (_Float16)b1[t]; sm.g1h[t] = (_Float16)g1[t]; sm.be1h[t] = (_Float16)be1[t]; }
  if (t < 128) { sm.b2h[t] = (_Float16)b2[t]; sm.g2h[t] = (_Float16)g2[t]; sm.be2h[t] = (_Float16)be2[t]; }
  if (t < 16) sm.muv[t] = mu[t];
  if (t < 8) sm.b3v[t] = (t < 5) ? b3[t] : 0.f;
  if (t < 64) {
    int e = base + t; int ec = e < EE ? e : EE - 1;
    sm.spI[t] = spawn[ec]; sm.exI[t] = exist[ec];
  }
  const float gma = gammaP[0];

  LBAR();   // B0: indices + consts visible

  // ---- precompute chunk-8 features into registers (t<64, wave 0) ----
  int4 f8a = {0,0,0,0}, f8b = {0,0,0,0};
  int k1 = 16, k2 = 32;
  if (t < 64) {
    int e = base + t; int ec = e < EE ? e : EE - 1;
    float ix0 = insx[ec * 3], ix1 = insx[ec * 3 + 1], ix2 = insx[ec * 3 + 2];
    int nd = sm.exI[t];
    float dx = ix0 - x[nd * 3], dy = ix1 - x[nd * 3 + 1], dz = ix2 - x[nd * 3 + 2];
    float d = fmaxf(sqrtf(dx * dx + dy * dy + dz * dz), 1e-6f);
    k1 = 16 + insa[ec]; k2 = 32 + insc[ec];
    float rb[16];
#pragma unroll
    for (int k = 0; k < 16; ++k) { float dd = d - sm.muv[k]; rb[k] = __expf(-gma * dd * dd); }
    uint4 ua, ub;
    ua.x = pkrtz(rb[0], rb[1]);  ua.y = pkrtz(rb[2], rb[3]);
    ua.z = pkrtz(rb[4], rb[5]);  ua.w = pkrtz(rb[6], rb[7]);
    ub.x = pkrtz(rb[8], rb[9]);  ub.y = pkrtz(rb[10], rb[11]);
    ub.z = pkrtz(rb[12], rb[13]); ub.w = pkrtz(rb[14], rb[15]);
    f8a = *(int4*)&ua; f8b = *(int4*)&ub;
  }

  // gather slots: each of 512 threads fills exactly one (row, 16B piece)
  const int row0 = t >> 3, p0 = t & 7;
  const int sw0 = ((p0 ^ (row0 & 7)) << 3);

  // chunk 0 gather (spawn, colb=0)
  int4 pA;
  if (use_hb) {
    pA = *(const int4*)(hb + (size_t)sm.spI[row0] * HIDD + p0 * 8);
  } else {
    pA = cvt_row(h + (size_t)sm.spI[row0] * HIDD + p0 * 8);
  }
  // write chunk 0 -> buf0
  *(int4*)&sm.r1[row0 * 64 + sw0] = pA;
  // issue chunk 1 gather (spawn, colb=64)
  if (use_hb) {
    pA = *(const int4*)(hb + (size_t)sm.spI[row0] * HIDD + 64 + p0 * 8);
  } else {
    pA = cvt_row(h + (size_t)sm.spI[row0] * HIDD + 64 + p0 * 8);
  }

  // W1 fragment base (direct global->reg); wave wv owns channels wv*32..wv*32+31
  const unsigned short* w1p = w1sw + q * 2048 + wv * 256 + cl * 8;
  half8 fcur[4], fnext[4];
#pragma unroll
  for (int ks = 0; ks < 2; ++ks)
#pragma unroll
    for (int i = 0; i < 2; ++i)
      fcur[ks * 2 + i] = ldg8(w1p + ks * 8192 + i * 128);

  LBAR();   // buf0 visible

  // ---- GEMM1: z1^T[256][64] = W1^T * feats^T, K = 576 in 9 chunks of 64 ----
  f32x4 acc[2][4];
#pragma unroll
  for (int i = 0; i < 2; ++i)
#pragma unroll
    for (int j = 0; j < 4; ++j) acc[i][j] = (f32x4){0.f, 0.f, 0.f, 0.f};

#pragma unroll
  for (int c = 0; c < 9; ++c) {
    // stage feats chunk c+1 into buf[(c+1)&1]; prefetch chunk c+2
    if (c < 7) {
      const int nb = ((c + 1) & 1) * 4096;
      *(int4*)&sm.r1[nb + row0 * 64 + sw0] = pA;   // vmcnt wait auto (data dep)
      if (c < 6) {
        const int cn = c + 2;
        const int* sel = (cn < 4) ? sm.spI : sm.exI;
        const int colb = (cn & 3) * 64;
        if (use_hb) {
          pA = *(const int4*)(hb + (size_t)sel[row0] * HIDD + colb + p0 * 8);
        } else {
          pA = cvt_row(h + (size_t)sel[row0] * HIDD + colb + p0 * 8);
        }
      }
    } else if (c == 7) {
      // chunk 8 = built features -> buf0, from precomputed regs (wave 0)
      if (t < 64) {
        short* rp = &sm.r1[t * 64];   // (8&1)=0 -> buf0
        const int sw = t & 7;
#pragma unroll
        for (int g = 0; g < 8; ++g) {
          int4 v = (g == 0) ? f8a : (g == 1) ? f8b : (int4){0, 0, 0, 0};
          *(int4*)&rp[(g ^ sw) * 8] = v;
        }
        rp[((k1 >> 3) ^ sw) * 8 + (k1 & 7)] = (short)0x3C00;   // fp16 1.0
        rp[((k2 >> 3) ^ sw) * 8 + (k2 & 7)] = (short)0x3C00;
      }
    }
    // prefetch W1 frags for chunk c+1 (regs)
    if (c < 8) {
      const unsigned short* wp = w1p + (c + 1) * 16384;
#pragma unroll
      for (int ks = 0; ks < 2; ++ks)
#pragma unroll
        for (int i = 0; i < 2; ++i)
          fnext[ks * 2 + i] = ldg8(wp + ks * 8192 + i * 128);
    }
    // MFMA chunk c from buf[c&1] + fcur
    const int cb = (c & 1) * 4096;
#pragma unroll
    for (int ks = 0; ks < 2; ++ks) {
      half8 bf[4];
#pragma unroll
      for (int j = 0; j < 4; ++j)
        bf[j] = *(const half8*)&sm.r1[cb + (j * 16 + cl) * 64 + ((ks * 32 + q * 8) ^ sx)];
#pragma unroll
      for (int i = 0; i < 2; ++i)
#pragma unroll
        for (int j = 0; j < 4; ++j)
          acc[i][j] = __builtin_amdgcn_mfma_f32_16x16x32_f16(fcur[ks * 2 + i], bf[j], acc[i][j], 0, 0, 0);
    }
#pragma unroll
    for (int u = 0; u < 4; ++u) fcur[u] = fnext[u];
    LBAR();   // chunk c+1 writes visible; all waves done with buf[c&1]
  }

  // ---- +b1 (fused), LN over 256 channels, SiLU, pack to z1T ----
  // packed-f32 (v_pk_add/v_pk_fma) epilogue
  f32x2 bb1[2][2];
#pragma unroll
  for (int i = 0; i < 2; ++i) {
    half4 b4 = *(const half4*)&sm.b1h[wv * 32 + i * 16 + q * 4];
    bb1[i][0] = (f32x2){(float)b4[0], (float)b4[1]};
    bb1[i][1] = (f32x2){(float)b4[2], (float)b4[3]};
  }
  float S1arr[4], Q1arr[4];
#pragma unroll
  for (int j = 0; j < 4; ++j) {
    f32x2 S2 = (f32x2){0.f, 0.f}, Q2 = (f32x2){0.f, 0.f};
#pragma unroll
    for (int i = 0; i < 2; ++i) {
      f32x2 v0 = (f32x2){acc[i][j][0], acc[i][j][1]} + bb1[i][0];
      f32x2 v1 = (f32x2){acc[i][j][2], acc[i][j][3]} + bb1[i][1];
      acc[i][j][0] = v0[0]; acc[i][j][1] = v0[1];
      acc[i][j][2] = v1[0]; acc[i][j][3] = v1[1];
      S2 += v0 + v1;
      Q2 += v0 * v0;        // contracts to v_pk_fma_f32
      Q2 += v1 * v1;
    }
    float S = S2[0] + S2[1], Q = Q2[0] + Q2[1];
    S += __shfl_xor(S, 16); S += __shfl_xor(S, 32);
    Q += __shfl_xor(Q, 16); Q += __shfl_xor(Q, 32);
    S1arr[j] = S; Q1arr[j] = Q;
  }
  if (q == 0) {
#pragma unroll
    for (int j = 0; j < 4; ++j) {
      sm.red[wv * 64 + j * 16 + cl] = S1arr[j];
      sm.red[512 + wv * 64 + j * 16 + cl] = Q1arr[j];
    }
  }
  LBAR();   // red1 visible; all waves past GEMM1 -> r1 reusable as z1T
  f32x2 rs1[4], mr1[4];      // {rstd,rstd}, {-mean*rstd,-mean*rstd}
#pragma unroll
  for (int j = 0; j < 4; ++j) {
    int m = j * 16 + cl;
    float S = 0.f, Q = 0.f;
#pragma unroll
    for (int w = 0; w < 8; ++w) { S += sm.red[w * 64 + m]; Q += sm.red[512 + w * 64 + m]; }
    float mn = S * (1.f / 256.f);
    float rs = rsqrtf(Q * (1.f / 256.f) - mn * mn + LN_EPS);
    rs1[j] = (f32x2){rs, rs};
    mr1[j] = (f32x2){-mn * rs, -mn * rs};
  }
#pragma unroll
  for (int i = 0; i < 2; ++i) {
    half4 g4 = *(const half4*)&sm.g1h[wv * 32 + i * 16 + q * 4];
    half4 e4 = *(const half4*)&sm.be1h[wv * 32 + i * 16 + q * 4];
    f32x2 gg0 = (f32x2){(float)g4[0], (float)g4[1]}, gg1 = (f32x2){(float)g4[2], (float)g4[3]};
    f32x2 ee0 = (f32x2){(float)e4[0], (float)e4[1]}, ee1 = (f32x2){(float)e4[2], (float)e4[3]};
#pragma unroll
    for (int j = 0; j < 4; ++j) {
      f32x2 v0 = (f32x2){acc[i][j][0], acc[i][j][1]};
      f32x2 v1 = (f32x2){acc[i][j][2], acc[i][j][3]};
      f32x2 t0 = v0 * rs1[j] + mr1[j];    // (v-mean)*rstd as one pk_fma
      f32x2 t1 = v1 * rs1[j] + mr1[j];
      f32x2 y0 = t0 * gg0 + ee0;
      f32x2 y1 = t1 * gg1 + ee1;
      float s0 = fast_silu(y0[0]), s1 = fast_silu(y0[1]);
      float s2 = fast_silu(y1[0]), s3 = fast_silu(y1[1]);
      uint2 w; w.x = pkrtz(s0, s1); w.y = pkrtz(s2, s3);
      int m = j * 16 + cl;
      int k0 = wv * 32 + i * 16 + q * 4;
      *(uint2*)&sm.r1[m * 256 + (k0 ^ ((m & 7) << 3))] = w;   // z1T swz
    }
  }
  LBAR();   // z1T visible

  // W3 fragments (waves 0-3 only): issue early, consumed at GEMM3
  half8 af3[4];
  if (wv < 4) {
#pragma unroll
    for (int ks = 0; ks < 4; ++ks)
      af3[ks] = ldg8(w3swg + (ks * 4 + q) * 128 + cl * 8);
  }

  // ---- GEMM2: z2^T[128][64] = W2^T * z1^T — barrier-free, W2 direct-to-reg ----
  // wave wv owns output channels wv*16..wv*16+15
  const unsigned short* w2p = w2sw + q * 1024 + wv * 128 + cl * 8;
  f32x4 acc2[4];
#pragma unroll
  for (int j = 0; j < 4; ++j) acc2[j] = (f32x4){0.f, 0.f, 0.f, 0.f};
#pragma unroll
  for (int c2 = 0; c2 < 4; ++c2) {
#pragma unroll
    for (int ks = 0; ks < 2; ++ks) {
      half8 a0 = ldg8(w2p + c2 * 8192 + ks * 4096);
      half8 bf[4];
#pragma unroll
      for (int j = 0; j < 4; ++j)
        bf[j] = *(const half8*)&sm.r1[(j * 16 + cl) * 256 + ((c2 * 64 + ks * 32 + q * 8) ^ sx)];
#pragma unroll
      for (int j = 0; j < 4; ++j)
        acc2[j] = __builtin_amdgcn_mfma_f32_16x16x32_f16(a0, bf[j], acc2[j], 0, 0, 0);
    }
  }

  // ---- +b2 (fused), LN over 128, SiLU, pack z2T (overlays z1T head in r1) ----
  f32x2 bb2[2];
  {
    half4 b4 = *(const half4*)&sm.b2h[wv * 16 + q * 4];
    bb2[0] = (f32x2){(float)b4[0], (float)b4[1]};
    bb2[1] = (f32x2){(float)b4[2], (float)b4[3]};
  }
  float S2arr[4], Q2arr[4];
#pragma unroll
  for (int j = 0; j < 4; ++j) {
    f32x2 v0 = (f32x2){acc2[j][0], acc2[j][1]} + bb2[0];
    f32x2 v1 = (f32x2){acc2[j][2], acc2[j][3]} + bb2[1];
    acc2[j][0] = v0[0]; acc2[j][1] = v0[1];
    acc2[j][2] = v1[0]; acc2[j][3] = v1[1];
    f32x2 S2 = v0 + v1;
    f32x2 Q2 = v0 * v0;
    Q2 += v1 * v1;
    float S = S2[0] + S2[1], Q = Q2[0] + Q2[1];
    S += __shfl_xor(S, 16); S += __shfl_xor(S, 32);
    Q += __shfl_xor(Q, 16); Q += __shfl_xor(Q, 32);
    S2arr[j] = S; Q2arr[j] = Q;
  }
  if (q == 0) {
#pragma unroll
    for (int j = 0; j < 4; ++j) {
      sm.red[wv * 64 + j * 16 + cl] = S2arr[j];
      sm.red[512 + wv * 64 + j * 16 + cl] = Q2arr[j];
    }
  }
  LBAR();   // red2 visible; all waves past GEMM2 -> z1T dead, z2T region safe
  f32x2 rs2[4], mr2[4];
#pragma unroll
  for (int j = 0; j < 4; ++j) {
    int m = j * 16 + cl;
    float S = 0.f, Q = 0.f;
#pragma unroll
    for (int w = 0; w < 8; ++w) { S += sm.red[w * 64 + m]; Q += sm.red[512 + w * 64 + m]; }
    float mn = S * (1.f / 128.f);
    float rs = rsqrtf(Q * (1.f / 128.f) - mn * mn + LN_EPS);
    rs2[j] = (f32x2){rs, rs};
    mr2[j] = (f32x2){-mn * rs, -mn * rs};
  }
  {
    half4 g4 = *(const half4*)&sm.g2h[wv * 16 + q * 4];
    half4 e4 = *(const half4*)&sm.be2h[wv * 16 + q * 4];
    f32x2 gg0 = (f32x2){(float)g4[0], (float)g4[1]}, gg1 = (f32x2){(float)g4[2], (float)g4[3]};
    f32x2 ee0 = (f32x2){(float)e4[0], (float)e4[1]}, ee1 = (f32x2){(float)e4[2], (float)e4[3]};
#pragma unroll
    for (int j = 0; j < 4; ++j) {
      f32x2 v0 = (f32x2){acc2[j][0], acc2[j][1]};
      f32x2 v1 = (f32x2){acc2[j][2], acc2[j][3]};
      f32x2 t0 = v0 * rs2[j] + mr2[j];
      f32x2 t1 = v1 * rs2[j] + mr2[j];
      f32x2 y0 = t0 * gg0 + ee0;
      f32x2 y1 = t1 * gg1 + ee1;
      float s0 = fast_silu(y0[0]), s1 = fast_silu(y0[1]);
      float s2 = fast_silu(y1[0]), s3 = fast_silu(y1[1]);
      uint2 w; w.x = pkrtz(s0, s1); w.y = pkrtz(s2, s3);
      int m = j * 16 + cl;
      int k0 = wv * 16 + q * 4;
      *(uint2*)&sm.r1[m * 128 + (k0 ^ ((m & 7) << 3))] = w;   // z2T swz (r1 head)
    }
  }
  LBAR();   // z2T visible

  // ---- GEMM3: out^T[16][64] = W3^T * z2^T (o padded 5->16), waves 0-3 ----
  if (wv < 4) {
    f32x4 a3 = (f32x4){0.f, 0.f, 0.f, 0.f};
    const int m3 = wv * 16 + cl;
    const int sx3 = (m3 & 7) << 3;
#pragma unroll
    for (int ks = 0; ks < 4; ++ks) {
      half8 bfv = *(const half8*)&sm.r1[m3 * 128 + ((ks * 32 + q * 8) ^ sx3)];
      a3 = __builtin_amdgcn_mfma_f32_16x16x32_f16(af3[ks], bfv, a3, 0, 0, 0);
    }
    // stage the 64x5 tile in LDS (red[] dead after LN2 reads) -> coalesced stores
#pragma unroll
    for (int r = 0; r < 4; ++r) {
      int o = q * 4 + r;
      if (o < 5) sm.red[m3 * 5 + o] = a3[r] + sm.b3v[o];
    }
  }
  LBAR();   // out tile visible
  if (t < 80) {
    size_t g = (size_t)base * 5 + (size_t)t * 4;
    if (g + 4 <= (size_t)EE * 5) {
      *(float4*)(out + g) = *(const float4*)&sm.red[t * 4];
    } else {
#pragma unroll
      for (int u = 0; u < 4; ++u)
        if (g + u < (size_t)EE * 5) out[g + u] = sm.red[t * 4 + u];
    }
  }
}

extern "C" void kernel_launch(void* const* d_in, const int* in_sizes, int n_in,
                              void* d_out, int out_size, void* d_ws, size_t ws_size,
                              hipStream_t stream) {
  const float* h    = (const float*)d_in[0];
  const float* x    = (const float*)d_in[1];
  const int* spawn  = (const int*)d_in[2];
  const int* exist  = (const int*)d_in[3];
  const float* insx = (const float*)d_in[4];
  const int* insa   = (const int*)d_in[5];
  const int* insc   = (const int*)d_in[6];
  const float* W1   = (const float*)d_in[7];
  const float* b1   = (const float*)d_in[8];
  const float* g1   = (const float*)d_in[9];
  const float* be1  = (const float*)d_in[10];
  const float* W2   = (const float*)d_in[11];
  const float* b2   = (const float*)d_in[12];
  const float* g2   = (const float*)d_in[13];
  const float* be2  = (const float*)d_in[14];
  const float* W3   = (const float*)d_in[15];
  const float* b3   = (const float*)d_in[16];
  const float* mu   = (const float*)d_in[17];
  const float* gma  = (const float*)d_in[18];

  unsigned short* w1sw = (unsigned short*)d_ws;          // 147456 el
  unsigned short* w2sw = w1sw + 147456;                  // 32768 el
  unsigned short* w3sw = w2sw + 32768;                   // 2048 el
  unsigned short* hb   = w3sw + 2048;                    // N*HID el (optional)
  const size_t need_hb = 364544ull + (size_t)NN * HIDD * 2ull;
  int use_hb = (ws_size >= need_hb) ? 1 : 0;

  prep_kern<<<use_hb ? 13212 : 712, 256, 0, stream>>>(h, W1, W2, W3, hb, w1sw, w2sw, w3sw);
  edge_head_main<<<7813, 512, 0, stream>>>(h, x, spawn, exist, insx, insa, insc,
                                           b1, g1, be1, b2, g2, be2, b3, mu, gma,
                                           w1sw, w2sw, w3sw, hb, use_hb,
                                           (float*)d_out);
}

// Round 3
// 419.612 us; speedup vs baseline: 1.4715x; 1.1732x over previous
//
#include <hip/hip_runtime.h>
#include <stdint.h>

#define NN 100000      // nodes
#define EE 500000      // edges
#define HIDD 256
#define LN_EPS 1e-5f

typedef _Float16 half8 __attribute__((ext_vector_type(8)));  // 8 fp16 (4 VGPRs)
typedef _Float16 half4 __attribute__((ext_vector_type(4)));
typedef __fp16 fp16x2 __attribute__((ext_vector_type(2)));   // builtin return type
typedef float f32x4 __attribute__((ext_vector_type(4)));
typedef float f32x2 __attribute__((ext_vector_type(2)));     // v_pk_*_f32 carrier

// lgkm-only barrier: makes LDS writes visible WITHOUT draining vmcnt (global loads
// stay in flight across it — the fine-grained vmcnt pattern __syncthreads forbids).
#define LBAR() asm volatile("s_waitcnt lgkmcnt(0)\n\ts_barrier" ::: "memory")

__device__ __forceinline__ unsigned short f2h(float f) {
  _Float16 h = (_Float16)f;                 // v_cvt_f16_f32, RNE
  union { _Float16 hh; unsigned short us; } u; u.hh = h;
  return u.us;
}

__device__ __forceinline__ unsigned pkrtz(float a, float b) {
  union { fp16x2 h; unsigned u; } c;
  c.h = __builtin_amdgcn_cvt_pkrtz(a, b);   // 1 instr: 2×f32 -> packed fp16
  return c.u;
}

__device__ __forceinline__ float fast_silu(float y) {
  float e = __expf(-y);
  return y * __builtin_amdgcn_rcpf(1.f + e);     // rcp instead of full div
}

__device__ __forceinline__ half8 ldg8(const unsigned short* p) {
  return *(const half8*)p;                  // global_load_dwordx4
}

// fp32 row-piece -> packed fp16 int4 (use_hb=0 fallback)
__device__ __forceinline__ int4 cvt_row(const float* s) {
  float4 a0 = *(const float4*)s, a1 = *(const float4*)(s + 4);
  uint4 ua;
  ua.x = pkrtz(a0.x, a0.y); ua.y = pkrtz(a0.z, a0.w);
  ua.z = pkrtz(a1.x, a1.y); ua.w = pkrtz(a1.z, a1.w);
  return *(int4*)&ua;
}

// ---- merged prep: weight swizzle (blocks 0..711) + h f32->fp16 (blocks 712..13211) ----
__global__ __launch_bounds__(256) void prep_kern(const float* __restrict__ h,
                                                 const float* __restrict__ W1,
                                                 const float* __restrict__ W2,
                                                 const float* __restrict__ W3,
                                                 unsigned short* __restrict__ hb,
                                                 unsigned short* __restrict__ w1sw,
                                                 unsigned short* __restrict__ w2sw,
                                                 unsigned short* __restrict__ w3sw) {
  int b = blockIdx.x;
  if (b < 712) {
    int t = b * 256 + threadIdx.x;
    if (t < 147456) {
      int chunk = t >> 14, rem = t & 16383;
      int kq = rem >> 11, n = (rem >> 3) & 255, j = rem & 7;
      int k = (chunk << 6) + (kq << 3) + j;
      float v = (k < 551) ? W1[k * 256 + n] : 0.f;
      w1sw[t] = f2h(v);
    } else if (t < 147456 + 32768) {
      int t2 = t - 147456;
      int chunk = t2 >> 13, rem = t2 & 8191;
      int kq = rem >> 10, n = (rem >> 3) & 127, j = rem & 7;
      int k = (chunk << 6) + (kq << 3) + j;
      w2sw[t2] = f2h(W2[k * 128 + n]);
    } else if (t < 147456 + 32768 + 2048) {
      int t3 = t - 180224;
      int kq = t3 >> 7, o = (t3 >> 3) & 15, j = t3 & 7;
      int k = (kq << 3) + j;
      w3sw[t3] = f2h((o < 5) ? W3[k * 5 + o] : 0.f);
    }
  } else {
    int i = ((b - 712) * 256 + threadIdx.x) * 8;   // N*HID = 25.6M = 12500*256*8
    float4 v0 = *(const float4*)(h + i);
    float4 v1 = *(const float4*)(h + i + 4);
    uint4 u;
    u.x = pkrtz(v0.x, v0.y); u.y = pkrtz(v0.z, v0.w);
    u.z = pkrtz(v1.x, v1.y); u.w = pkrtz(v1.z, v1.w);
    *(uint4*)(hb + i) = u;
  }
}

// ---- fused main kernel: 64 edges/block, 256 threads (4 waves), 3 blocks/CU ----
// Round-1/2 lessons: (r1) 4 blk/CU at 256t spills (148 live regs > 128 budget);
// (r2) 8-wave blocks at 16 waves/CU are SLOWER (finer barrier phases, worse
// stragglers). So: keep the round-0 shape (12 waves/CU) and shorten the per-chunk
// latency chain instead:
//   * features chunk reordered to logical chunk 0 (built pre-loop) -> uniform
//     8-chunk gather stream with loads issued 2 phases ahead (covers random
//     L2/L3 gather latency + per-barrier straggler tail).
//   * gather base pointers hoisted; per-chunk offsets are load-immediates
//     (zero per-chunk address VALU; no LDS index re-reads across barriers).
//   * W1 frags fA/fB half-rotation (32 regs, reload-after-use) instead of full
//     dbuf (64) -> total ~135 regs, real headroom under the 168 budget of (256,3).
// W1/W2/W3 fragments load DIRECTLY global->VGPR; LDS holds block-local data only.
// All barriers lgkm-only. Swizzle: elem(row,k) at row*S + (k ^ ((row&7)<<3)).
// A-frag: A[m=lane&15][k=(lane>>4)*8+j];  B-frag: B[k=(lane>>4)*8+j][n=lane&15]
// D: row m=(lane>>4)*4+reg (channel), col n=lane&15 (edge)
struct __align__(16) SMem {
  short r1[16384];    // 32768B: feats dbuf (2x4096el) in GEMM1 -> z1T [64][256]swz -> z2T [64][128]swz (head)
  float red[512];     // 2048B : LN partials (S [0..255], Q [256..511]) -> out staging (320f)
  _Float16 b1h[256], g1h[256], be1h[256];   // 1536B
  _Float16 b2h[128], g2h[128], be2h[128];   // 768B
  float muv[16];      // 64B
  float b3v[8];       // 32B
  int spI[64], exI[64];                     // 512B
};  // ~37.7 KB

__global__ __launch_bounds__(256, 3)
void edge_head_main(const float* __restrict__ h, const float* __restrict__ x,
                    const int* __restrict__ spawn, const int* __restrict__ exist,
                    const float* __restrict__ insx, const int* __restrict__ insa,
                    const int* __restrict__ insc,
                    const float* __restrict__ b1, const float* __restrict__ g1,
                    const float* __restrict__ be1,
                    const float* __restrict__ b2, const float* __restrict__ g2,
                    const float* __restrict__ be2,
                    const float* __restrict__ b3, const float* __restrict__ mu,
                    const float* __restrict__ gammaP,
                    const unsigned short* __restrict__ w1sw,
                    const unsigned short* __restrict__ w2sw,
                    const unsigned short* __restrict__ w3swg,
                    const unsigned short* __restrict__ hb, int use_hb,
                    float* __restrict__ out) {
  __shared__ SMem sm;
  const int t = threadIdx.x;
  const int base = blockIdx.x * 64;
  const int lane = t & 63;
  const int wv = t >> 6;
  const int cl = lane & 15;
  const int q = lane >> 4;
  const int sx = (cl & 7) << 3;    // B-frag read swizzle term

  // ---- const staging ----
  sm.b1h[t] = (_Float16)b1[t]; sm.g1h[t] = (_Float16)g1[t]; sm.be1h[t] = (_Float16)be1[t];
  if (t < 128) { sm.b2h[t] = (_Float16)b2[t]; sm.g2h[t] = (_Float16)g2[t]; sm.be2h[t] = (_Float16)be2[t]; }
  if (t < 16) sm.muv[t] = mu[t];
  if (t < 8) sm.b3v[t] = (t < 5) ? b3[t] : 0.f;
  if (t < 64) {
    int e = base + t; int ec = e < EE ? e : EE - 1;
    sm.spI[t] = spawn[ec]; sm.exI[t] = exist[ec];
  }
  const float gma = gammaP[0];

  LBAR();   // B0: indices + consts visible

  // ---- distance / one-hot prep for the features chunk (t<64, wave 0) ----
  float dreg = 0.f;
  int k1 = 16, k2 = 32;
  if (t < 64) {
    int e = base + t; int ec = e < EE ? e : EE - 1;
    float ix0 = insx[ec * 3], ix1 = insx[ec * 3 + 1], ix2 = insx[ec * 3 + 2];
    int nd = sm.exI[t];
    float dx = ix0 - x[nd * 3], dy = ix1 - x[nd * 3 + 1], dz = ix2 - x[nd * 3 + 2];
    dreg = fmaxf(sqrtf(dx * dx + dy * dy + dz * dz), 1e-6f);
    k1 = 16 + insa[ec]; k2 = 32 + insc[ec];
  }

  // gather slots: thread fills feats rows row0 (16B piece p0) and row1 (=row0+32)
  const int row0 = t >> 3, p0 = t & 7;
  const int row1 = row0 + 32;
  const int sw0 = ((p0 ^ (row0 & 7)) << 3);
  const int sw1 = ((p0 ^ (row1 & 7)) << 3);

  // hoisted gather base pointers (byte-typed so chunk offsets fold to load imms)
  const size_t oSp0 = (size_t)sm.spI[row0] * HIDD + p0 * 8;
  const size_t oSp1 = (size_t)sm.spI[row1] * HIDD + p0 * 8;
  const size_t oEx0 = (size_t)sm.exI[row0] * HIDD + p0 * 8;
  const size_t oEx1 = (size_t)sm.exI[row1] * HIDD + p0 * 8;
  const char* bSp0 = use_hb ? (const char*)(hb + oSp0) : (const char*)(h + oSp0);
  const char* bSp1 = use_hb ? (const char*)(hb + oSp1) : (const char*)(h + oSp1);
  const char* bEx0 = use_hb ? (const char*)(hb + oEx0) : (const char*)(h + oEx0);
  const char* bEx1 = use_hb ? (const char*)(hb + oEx1) : (const char*)(h + oEx1);

  // logical chunk lc (1..8) -> physical gather g = lc-1; sel = g<4 ? spawn : exist
#define GLOAD(lc, PA, PB) do {                                          \
    const int g_ = (lc) - 1;                                            \
    const int colb_ = (g_ & 3) * 64;                                    \
    const char* b0_ = (g_ < 4) ? bSp0 : bEx0;                           \
    const char* b1_ = (g_ < 4) ? bSp1 : bEx1;                           \
    if (use_hb) {                                                       \
      PA = *(const int4*)(b0_ + colb_ * 2);                             \
      PB = *(const int4*)(b1_ + colb_ * 2);                             \
    } else {                                                            \
      PA = cvt_row((const float*)(b0_ + colb_ * 4));                    \
      PB = cvt_row((const float*)(b1_ + colb_ * 4));                    \
    }                                                                   \
  } while (0)

  // issue loads for logical chunks 1 and 2 (consumed at iters 0 and 1)
  int4 pA1, pB1, pA0, pB0;
  GLOAD(1, pA1, pB1);
  GLOAD(2, pA0, pB0);

  // W1 fragment base; preload logical chunk 0 = PHYSICAL chunk 8 (feature rows)
  const unsigned short* w1p = w1sw + q * 2048 + wv * 512 + cl * 8;
  half8 fA[4], fB[4];
#pragma unroll
  for (int i = 0; i < 4; ++i) fA[i] = ldg8(w1p + 8 * 16384 + i * 128);
#pragma unroll
  for (int i = 0; i < 4; ++i) fB[i] = ldg8(w1p + 8 * 16384 + 8192 + i * 128);

  // ---- build features chunk (logical 0) -> buf0, wave 0 ----
  if (t < 64) {
    short* rp = &sm.r1[t * 64];
    const int sw = t & 7;
    float rb[16];
#pragma unroll
    for (int k = 0; k < 16; ++k) { float dd = dreg - sm.muv[k]; rb[k] = __expf(-gma * dd * dd); }
    uint4 ua, ub;
    ua.x = pkrtz(rb[0], rb[1]);  ua.y = pkrtz(rb[2], rb[3]);
    ua.z = pkrtz(rb[4], rb[5]);  ua.w = pkrtz(rb[6], rb[7]);
    ub.x = pkrtz(rb[8], rb[9]);  ub.y = pkrtz(rb[10], rb[11]);
    ub.z = pkrtz(rb[12], rb[13]); ub.w = pkrtz(rb[14], rb[15]);
    *(int4*)&rp[(0 ^ sw) * 8] = *(int4*)&ua;
    *(int4*)&rp[(1 ^ sw) * 8] = *(int4*)&ub;
    const int4 z4 = {0, 0, 0, 0};
#pragma unroll
    for (int g = 2; g < 8; ++g) *(int4*)&rp[(g ^ sw) * 8] = z4;
    rp[((k1 >> 3) ^ sw) * 8 + (k1 & 7)] = (short)0x3C00;   // fp16 1.0
    rp[((k2 >> 3) ^ sw) * 8 + (k2 & 7)] = (short)0x3C00;
  }

  LBAR();   // buf0 (features) visible

  // ---- GEMM1: z1^T[256][64] = W1^T * feats^T, K = 576 in 9 chunks of 64 ----
  // logical c: 0=features (phys 8), 1..8 = gather chunks (phys 0..7)
  f32x4 acc[4][4];
#pragma unroll
  for (int i = 0; i < 4; ++i)
#pragma unroll
    for (int j = 0; j < 4; ++j) acc[i][j] = (f32x4){0.f, 0.f, 0.f, 0.f};

#pragma unroll
  for (int c = 0; c < 9; ++c) {
    // stage logical chunk c+1 into buf[(c+1)&1]; issue load for logical c+3
    if (c < 8) {
      const int nb = ((c + 1) & 1) * 4096;
      if ((c & 1) == 0) {          // c+1 odd -> set1
        *(int4*)&sm.r1[nb + row0 * 64 + sw0] = pA1;   // vmcnt wait auto (data dep)
        *(int4*)&sm.r1[nb + row1 * 64 + sw1] = pB1;
        if (c <= 5) GLOAD(c + 3, pA1, pB1);
      } else {                     // c+1 even -> set0
        *(int4*)&sm.r1[nb + row0 * 64 + sw0] = pA0;
        *(int4*)&sm.r1[nb + row1 * 64 + sw1] = pB0;
        if (c <= 5) GLOAD(c + 3, pA0, pB0);
      }
    }
    // MFMA logical chunk c from buf[c&1]; fA/fB reload right after use
    const int cb = (c & 1) * 4096;
    {
      half8 bf[4];
#pragma unroll
      for (int j = 0; j < 4; ++j)
        bf[j] = *(const half8*)&sm.r1[cb + (j * 16 + cl) * 64 + ((q * 8) ^ sx)];
#pragma unroll
      for (int i = 0; i < 4; ++i)
#pragma unroll
        for (int j = 0; j < 4; ++j)
          acc[i][j] = __builtin_amdgcn_mfma_f32_16x16x32_f16(fA[i], bf[j], acc[i][j], 0, 0, 0);
    }
    if (c < 8) {   // logical c+1 -> physical c
      const unsigned short* wp = w1p + c * 16384;
#pragma unroll
      for (int i = 0; i < 4; ++i) fA[i] = ldg8(wp + i * 128);
    }
    {
      half8 bf[4];
#pragma unroll
      for (int j = 0; j < 4; ++j)
        bf[j] = *(const half8*)&sm.r1[cb + (j * 16 + cl) * 64 + ((32 + q * 8) ^ sx)];
#pragma unroll
      for (int i = 0; i < 4; ++i)
#pragma unroll
        for (int j = 0; j < 4; ++j)
          acc[i][j] = __builtin_amdgcn_mfma_f32_16x16x32_f16(fB[i], bf[j], acc[i][j], 0, 0, 0);
    }
    if (c < 8) {
      const unsigned short* wp = w1p + c * 16384 + 8192;
#pragma unroll
      for (int i = 0; i < 4; ++i) fB[i] = ldg8(wp + i * 128);
    }
    LBAR();   // chunk c+1 writes visible; all waves done with buf[c&1]
  }
#undef GLOAD

  // ---- +b1 (fused), LN over 256 channels, SiLU, pack to z1T ----
  // packed-f32 (v_pk_add/v_pk_fma) epilogue
  f32x2 bb1[4][2];
#pragma unroll
  for (int i = 0; i < 4; ++i) {
    half4 b4 = *(const half4*)&sm.b1h[wv * 64 + i * 16 + q * 4];
    bb1[i][0] = (f32x2){(float)b4[0], (float)b4[1]};
    bb1[i][1] = (f32x2){(float)b4[2], (float)b4[3]};
  }
  float S1arr[4], Q1arr[4];
#pragma unroll
  for (int j = 0; j < 4; ++j) {
    f32x2 S2 = (f32x2){0.f, 0.f}, Q2 = (f32x2){0.f, 0.f};
#pragma unroll
    for (int i = 0; i < 4; ++i) {
      f32x2 v0 = (f32x2){acc[i][j][0], acc[i][j][1]} + bb1[i][0];
      f32x2 v1 = (f32x2){acc[i][j][2], acc[i][j][3]} + bb1[i][1];
      acc[i][j][0] = v0[0]; acc[i][j][1] = v0[1];
      acc[i][j][2] = v1[0]; acc[i][j][3] = v1[1];
      S2 += v0 + v1;
      Q2 += v0 * v0;        // contracts to v_pk_fma_f32
      Q2 += v1 * v1;
    }
    float S = S2[0] + S2[1], Q = Q2[0] + Q2[1];
    S += __shfl_xor(S, 16); S += __shfl_xor(S, 32);
    Q += __shfl_xor(Q, 16); Q += __shfl_xor(Q, 32);
    S1arr[j] = S; Q1arr[j] = Q;
  }
  if (q == 0) {
#pragma unroll
    for (int j = 0; j < 4; ++j) {
      sm.red[wv * 64 + j * 16 + cl] = S1arr[j];
      sm.red[256 + wv * 64 + j * 16 + cl] = Q1arr[j];
    }
  }
  LBAR();   // red1 visible; all waves past GEMM1 -> r1 reusable as z1T
  f32x2 rs1[4], mr1[4];      // {rstd,rstd}, {-mean*rstd,-mean*rstd}
#pragma unroll
  for (int j = 0; j < 4; ++j) {
    int m = j * 16 + cl;
    float S = sm.red[m] + sm.red[64 + m] + sm.red[128 + m] + sm.red[192 + m];
    float Q = sm.red[256 + m] + sm.red[320 + m] + sm.red[384 + m] + sm.red[448 + m];
    float mn = S * (1.f / 256.f);
    float rs = rsqrtf(Q * (1.f / 256.f) - mn * mn + LN_EPS);
    rs1[j] = (f32x2){rs, rs};
    mr1[j] = (f32x2){-mn * rs, -mn * rs};
  }
#pragma unroll
  for (int i = 0; i < 4; ++i) {
    half4 g4 = *(const half4*)&sm.g1h[wv * 64 + i * 16 + q * 4];
    half4 e4 = *(const half4*)&sm.be1h[wv * 64 + i * 16 + q * 4];
    f32x2 gg0 = (f32x2){(float)g4[0], (float)g4[1]}, gg1 = (f32x2){(float)g4[2], (float)g4[3]};
    f32x2 ee0 = (f32x2){(float)e4[0], (float)e4[1]}, ee1 = (f32x2){(float)e4[2], (float)e4[3]};
#pragma unroll
    for (int j = 0; j < 4; ++j) {
      f32x2 v0 = (f32x2){acc[i][j][0], acc[i][j][1]};
      f32x2 v1 = (f32x2){acc[i][j][2], acc[i][j][3]};
      f32x2 t0 = v0 * rs1[j] + mr1[j];    // (v-mean)*rstd as one pk_fma
      f32x2 t1 = v1 * rs1[j] + mr1[j];
      f32x2 y0 = t0 * gg0 + ee0;
      f32x2 y1 = t1 * gg1 + ee1;
      float s0 = fast_silu(y0[0]), s1 = fast_silu(y0[1]);
      float s2 = fast_silu(y1[0]), s3 = fast_silu(y1[1]);
      uint2 w; w.x = pkrtz(s0, s1); w.y = pkrtz(s2, s3);
      int m = j * 16 + cl;
      int k0 = wv * 64 + i * 16 + q * 4;
      *(uint2*)&sm.r1[m * 256 + (k0 ^ ((m & 7) << 3))] = w;   // z1T swz
    }
  }
  LBAR();   // z1T visible

  // W3 fragments: issue early, consumed at GEMM3 (vmcnt interleave)
  half8 af3[4];
#pragma unroll
  for (int ks = 0; ks < 4; ++ks)
    af3[ks] = ldg8(w3swg + (ks * 4 + q) * 128 + cl * 8);

  // ---- GEMM2: z2^T[128][64] = W2^T * z1^T — barrier-free, W2 direct-to-reg ----
  const unsigned short* w2p = w2sw + q * 1024 + wv * 256 + cl * 8;
  f32x4 acc2[2][4];
#pragma unroll
  for (int i = 0; i < 2; ++i)
#pragma unroll
    for (int j = 0; j < 4; ++j) acc2[i][j] = (f32x4){0.f, 0.f, 0.f, 0.f};
#pragma unroll
  for (int c2 = 0; c2 < 4; ++c2) {
#pragma unroll
    for (int ks = 0; ks < 2; ++ks) {
      half8 a0 = ldg8(w2p + c2 * 8192 + ks * 4096);
      half8 a1 = ldg8(w2p + c2 * 8192 + ks * 4096 + 128);
      half8 bf[4];
#pragma unroll
      for (int j = 0; j < 4; ++j)
        bf[j] = *(const half8*)&sm.r1[(j * 16 + cl) * 256 + ((c2 * 64 + ks * 32 + q * 8) ^ sx)];
#pragma unroll
      for (int j = 0; j < 4; ++j) {
        acc2[0][j] = __builtin_amdgcn_mfma_f32_16x16x32_f16(a0, bf[j], acc2[0][j], 0, 0, 0);
        acc2[1][j] = __builtin_amdgcn_mfma_f32_16x16x32_f16(a1, bf[j], acc2[1][j], 0, 0, 0);
      }
    }
  }

  // ---- +b2 (fused), LN over 128, SiLU, pack z2T (overlays z1T head in r1) ----
  f32x2 bb2[2][2];
#pragma unroll
  for (int i = 0; i < 2; ++i) {
    half4 b4 = *(const half4*)&sm.b2h[wv * 32 + i * 16 + q * 4];
    bb2[i][0] = (f32x2){(float)b4[0], (float)b4[1]};
    bb2[i][1] = (f32x2){(float)b4[2], (float)b4[3]};
  }
  float S2arr[4], Q2arr[4];
#pragma unroll
  for (int j = 0; j < 4; ++j) {
    f32x2 S2 = (f32x2){0.f, 0.f}, Q2 = (f32x2){0.f, 0.f};
#pragma unroll
    for (int i = 0; i < 2; ++i) {
      f32x2 v0 = (f32x2){acc2[i][j][0], acc2[i][j][1]} + bb2[i][0];
      f32x2 v1 = (f32x2){acc2[i][j][2], acc2[i][j][3]} + bb2[i][1];
      acc2[i][j][0] = v0[0]; acc2[i][j][1] = v0[1];
      acc2[i][j][2] = v1[0]; acc2[i][j][3] = v1[1];
      S2 += v0 + v1;
      Q2 += v0 * v0;
      Q2 += v1 * v1;
    }
    float S = S2[0] + S2[1], Q = Q2[0] + Q2[1];
    S += __shfl_xor(S, 16); S += __shfl_xor(S, 32);
    Q += __shfl_xor(Q, 16); Q += __shfl_xor(Q, 32);
    S2arr[j] = S; Q2arr[j] = Q;
  }
  if (q == 0) {
#pragma unroll
    for (int j = 0; j < 4; ++j) {
      sm.red[wv * 64 + j * 16 + cl] = S2arr[j];
      sm.red[256 + wv * 64 + j * 16 + cl] = Q2arr[j];
    }
  }
  LBAR();   // red2 visible; all waves past GEMM2 -> z1T dead, z2T region safe
  f32x2 rs2[4], mr2[4];
#pragma unroll
  for (int j = 0; j < 4; ++j) {
    int m = j * 16 + cl;
    float S = sm.red[m] + sm.red[64 + m] + sm.red[128 + m] + sm.red[192 + m];
    float Q = sm.red[256 + m] + sm.red[320 + m] + sm.red[384 + m] + sm.red[448 + m];
    float mn = S * (1.f / 128.f);
    float rs = rsqrtf(Q * (1.f / 128.f) - mn * mn + LN_EPS);
    rs2[j] = (f32x2){rs, rs};
    mr2[j] = (f32x2){-mn * rs, -mn * rs};
  }
#pragma unroll
  for (int i = 0; i < 2; ++i) {
    half4 g4 = *(const half4*)&sm.g2h[wv * 32 + i * 16 + q * 4];
    half4 e4 = *(const half4*)&sm.be2h[wv * 32 + i * 16 + q * 4];
    f32x2 gg0 = (f32x2){(float)g4[0], (float)g4[1]}, gg1 = (f32x2){(float)g4[2], (float)g4[3]};
    f32x2 ee0 = (f32x2){(float)e4[0], (float)e4[1]}, ee1 = (f32x2){(float)e4[2], (float)e4[3]};
#pragma unroll
    for (int j = 0; j < 4; ++j) {
      f32x2 v0 = (f32x2){acc2[i][j][0], acc2[i][j][1]};
      f32x2 v1 = (f32x2){acc2[i][j][2], acc2[i][j][3]};
      f32x2 t0 = v0 * rs2[j] + mr2[j];
      f32x2 t1 = v1 * rs2[j] + mr2[j];
      f32x2 y0 = t0 * gg0 + ee0;
      f32x2 y1 = t1 * gg1 + ee1;
      float s0 = fast_silu(y0[0]), s1 = fast_silu(y0[1]);
      float s2 = fast_silu(y1[0]), s3 = fast_silu(y1[1]);
      uint2 w; w.x = pkrtz(s0, s1); w.y = pkrtz(s2, s3);
      int m = j * 16 + cl;
      int k0 = wv * 32 + i * 16 + q * 4;
      *(uint2*)&sm.r1[m * 128 + (k0 ^ ((m & 7) << 3))] = w;   // z2T swz (r1 head)
    }
  }
  LBAR();   // z2T visible

  // ---- GEMM3: out^T[16][64] = W3^T * z2^T (o padded 5->16) ----
  f32x4 a3 = (f32x4){0.f, 0.f, 0.f, 0.f};
  const int m3 = wv * 16 + cl;
  const int sx3 = (m3 & 7) << 3;
#pragma unroll
  for (int ks = 0; ks < 4; ++ks) {
    half8 bfv = *(const half8*)&sm.r1[m3 * 128 + ((ks * 32 + q * 8) ^ sx3)];
    a3 = __builtin_amdgcn_mfma_f32_16x16x32_f16(af3[ks], bfv, a3, 0, 0, 0);
  }
  // stage the 64x5 output tile in LDS (red[] is dead) and write coalesced float4s
#pragma unroll
  for (int r = 0; r < 4; ++r) {
    int o = q * 4 + r;
    if (o < 5) sm.red[m3 * 5 + o] = a3[r] + sm.b3v[o];
  }
  LBAR();   // out tile visible
  if (t < 80) {
    size_t g = (size_t)base * 5 + (size_t)t * 4;
    if (g + 4 <= (size_t)EE * 5) {
      *(float4*)(out + g) = *(const float4*)&sm.red[t * 4];
    } else {
#pragma unroll
      for (int u = 0; u < 4; ++u)
        if (g + u < (size_t)EE * 5) out[g + u] = sm.red[t * 4 + u];
    }
  }
}

extern "C" void kernel_launch(void* const* d_in, const int* in_sizes, int n_in,
                              void* d_out, int out_size, void* d_ws, size_t ws_size,
                              hipStream_t stream) {
  const float* h    = (const float*)d_in[0];
  const float* x    = (const float*)d_in[1];
  const int* spawn  = (const int*)d_in[2];
  const int* exist  = (const int*)d_in[3];
  const float* insx = (const float*)d_in[4];
  const int* insa   = (const int*)d_in[5];
  const int* insc   = (const int*)d_in[6];
  const float* W1   = (const float*)d_in[7];
  const float* b1   = (const float*)d_in[8];
  const float* g1   = (const float*)d_in[9];
  const float* be1  = (const float*)d_in[10];
  const float* W2   = (const float*)d_in[11];
  const float* b2   = (const float*)d_in[12];
  const float* g2   = (const float*)d_in[13];
  const float* be2  = (const float*)d_in[14];
  const float* W3   = (const float*)d_in[15];
  const float* b3   = (const float*)d_in[16];
  const float* mu   = (const float*)d_in[17];
  const float* gma  = (const float*)d_in[18];

  unsigned short* w1sw = (unsigned short*)d_ws;          // 147456 el
  unsigned short* w2sw = w1sw + 147456;                  // 32768 el
  unsigned short* w3sw = w2sw + 32768;                   // 2048 el
  unsigned short* hb   = w3sw + 2048;                    // N*HID el (optional)
  const size_t need_hb = 364544ull + (size_t)NN * HIDD * 2ull;
  int use_hb = (ws_size >= need_hb) ? 1 : 0;

  prep_kern<<<use_hb ? 13212 : 712, 256, 0, stream>>>(h, W1, W2, W3, hb, w1sw, w2sw, w3sw);
  edge_head_main<<<7813, 256, 0, stream>>>(h, x, spawn, exist, insx, insa, insc,
                                           b1, g1, be1, b2, g2, be2, b3, mu, gma,
                                           w1sw, w2sw, w3sw, hb, use_hb,
                                           (float*)d_out);
}